// Round 11
// baseline (3941.586 us; speedup 1.0000x reference)
//
#include <hip/hip_runtime.h>

#define NBLK  256
#define NTHR  384
#define TDEC  128
#define TENC  256
#define DIN   256
#define DENC  512
#define HHH   512
#define NG    1536
#define KTOT  1280
#define NK4   320
#define ASTR  516          // padded [b][k] row stride in floats
#define ASTR4 129          // in float4

// ws float offsets
#define OFF_CNT   0                       // 128*16*4 u32 = 32768 B
#define OFF_U     8192                    // 1024
#define OFF_ECTX  9216                    // 64*256
#define OFF_HG    25600                   // 64*512
#define OFF_CTXG  58368                   // 64*512
#define OFF_RHG   91136                   // 64*512
#define OFF_WP    123904                  // 16*320*96*4 = 1,966,080 elems
#define WP_ELEMS  (16*NK4*96*4)

// ---------------- small helpers ----------------
__device__ __forceinline__ float wave_sum(float v) {
#pragma unroll
    for (int o = 32; o; o >>= 1) v += __shfl_down(v, o, 64);
    return v;
}
__device__ __forceinline__ float wave_max(float v) {
#pragma unroll
    for (int o = 32; o; o >>= 1) v = fmaxf(v, __shfl_down(v, o, 64));
    return v;
}
__device__ __forceinline__ float ldA(float* p) {
    return __hip_atomic_load(p, __ATOMIC_RELAXED, __HIP_MEMORY_SCOPE_AGENT);
}
__device__ __forceinline__ void stA(float* p, float v) {
    __hip_atomic_store(p, v, __ATOMIC_RELAXED, __HIP_MEMORY_SCOPE_AGENT);
}
// drain THIS wave's outstanding vector-memory stores. Every wave that
// published data must do this BEFORE the barrier preceding the arrive.
__device__ __forceinline__ void drain_stores() {
    asm volatile("s_waitcnt vmcnt(0)" ::: "memory");
}
__device__ __forceinline__ void arrive(unsigned* c) {
    asm volatile("s_waitcnt vmcnt(0)" ::: "memory");
    __hip_atomic_fetch_add(c, 1u, __ATOMIC_RELAXED, __HIP_MEMORY_SCOPE_AGENT);
}
__device__ __forceinline__ void wait16(unsigned* c) {
    while (__hip_atomic_load(c, __ATOMIC_RELAXED, __HIP_MEMORY_SCOPE_AGENT) < 16u)
        __builtin_amdgcn_s_sleep(2);
}
__device__ __forceinline__ float blo(unsigned u) { return __uint_as_float(u << 16); }
__device__ __forceinline__ float bhi(unsigned u) { return __uint_as_float(u & 0xffff0000u); }
__device__ __forceinline__ unsigned short f2bf(float f) {
    unsigned u = __float_as_uint(f);
    u += 0x7fffu + ((u >> 16) & 1u);
    return (unsigned short)(u >> 16);
}

// thread's partial dot over k4 in [k4lo,k4hi): weight (cg,k4,col),
// activation float4 at a4[b*ASTR4 + (k4 - aoff)]  ([b][k] padded layout)
template<bool BF>
__device__ __forceinline__ float dotrange(const void* wp, int cg, int col, int b,
                                          int k4lo, int k4hi, const float4* a4,
                                          int aoff, float acc) {
    const float4* ab = a4 + (size_t)b*ASTR4 - aoff;
    if (BF) {
        const uint2* w = (const uint2*)wp + (size_t)cg*NK4*96 + col;
#pragma unroll 8
        for (int k4 = k4lo; k4 < k4hi; ++k4) {
            uint2 uu = w[(size_t)k4 * 96];
            float4 a = ab[k4];
            acc = fmaf(blo(uu.x), a.x, acc);
            acc = fmaf(bhi(uu.x), a.y, acc);
            acc = fmaf(blo(uu.y), a.z, acc);
            acc = fmaf(bhi(uu.y), a.w, acc);
        }
    } else {
        const float4* w = (const float4*)wp + (size_t)cg*NK4*96 + col;
#pragma unroll 8
        for (int k4 = k4lo; k4 < k4hi; ++k4) {
            float4 wv = w[(size_t)k4 * 96];
            float4 a = ab[k4];
            acc = fmaf(wv.x, a.x, acc);
            acc = fmaf(wv.y, a.y, acc);
            acc = fmaf(wv.z, a.z, acc);
            acc = fmaf(wv.w, a.w, acc);
        }
    }
    return acc;
}

// ---------------- precompute kernels ----------------
__global__ void k_u(const float* __restrict__ w1, const float* __restrict__ w2,
                    float* __restrict__ u) {
    int e = blockIdx.x;
    int lane = threadIdx.x;
    float p = 0.f;
#pragma unroll
    for (int k = lane; k < DENC; k += 64) p += w1[e*DENC + k] * w2[k];
    p = wave_sum(p);
    if (lane == 0) u[e] = p;
}

__global__ void k_ectx(const float* __restrict__ C, const float* __restrict__ u,
                       float* __restrict__ ectx) {
    int r = blockIdx.x*4 + (threadIdx.x >> 6);
    int lane = threadIdx.x & 63;
    const float* row = C + (size_t)r*DENC;
    const float* vc  = u + HHH;
    float p = 0.f;
#pragma unroll
    for (int k = 0; k < DENC/64; ++k) p += row[lane + k*64] * vc[lane + k*64];
    p = wave_sum(p);
    if (lane == 0) ectx[r] = p;
}

// pack: [cg][k4][col96][e];  j_glob = (col>>5)*512 + cg*32 + (col&31);  k = k4*4+e
template<bool BF>
__global__ void k_wpack(const float* __restrict__ Wx, const float* __restrict__ Wh,
                        void* __restrict__ wp) {
    int id = blockIdx.x*256 + threadIdx.x;      // < WP_ELEMS
    int e = id & 3;
    int q = id >> 2;
    int col = q % 96;
    q /= 96;
    int k4 = q % NK4;
    int cg = q / NK4;
    int k = k4*4 + e;
    int j = (col >> 5)*512 + cg*32 + (col & 31);
    float v = (k < 768) ? Wx[(size_t)k*NG + j] : Wh[(size_t)(k-768)*NG + j];
    if (BF) ((unsigned short*)wp)[id] = f2bf(v);
    else    ((float*)wp)[id] = v;
}

// ---------------- main kernel ----------------
// 256 blocks = (bg = blk>>4) x (cg = blk&15): 4 batches x 96 cols (32 z, 32 r, 32 h).
// Attention role: b_att = blk>>2 (one of the block's own 4 batches), ds = blk&3.
// Thread: col = tid>>2, b = tid&3; sub = col>>5 (0=z,1=r,2=h), q32 = col&31.
template<bool BF>
__launch_bounds__(NTHR, 1)
__global__ void decoder(const float* __restrict__ inp, const float* __restrict__ C,
                        const float* __restrict__ bias, const void* __restrict__ wpv,
                        const float* __restrict__ u, float* __restrict__ ectx_g,
                        float* __restrict__ out, float* __restrict__ ws) {
    unsigned* cnt = (unsigned*)ws;
    float* hG   = ws + OFF_HG;
    float* ctxG = ws + OFF_CTXG;
    float* rhG  = ws + OFF_RHG;

    const int tid  = threadIdx.x;
    const int w    = tid >> 6;
    const int blk  = blockIdx.x;
    const int bg   = blk >> 4;
    const int cg   = blk & 15;
    const int b_att = blk >> 2;
    const int ds    = blk & 3;
    const int bl_att = b_att & 3;
    const int col  = tid >> 2;
    const int b    = tid & 3;
    const int sub  = col >> 5;
    const int q32  = col & 31;
    const int jp   = cg*32 + q32;
    const int bglob = bg*4 + b;

    __shared__ float sh_C[TENC*128];                 // 131 KB fp32 C slice [q][dp]
    __shared__ __align__(16) float sh_st[4*ASTR];    // staging [b][k] pad: x -> ctx -> rh
    __shared__ __align__(16) float sh_h[4*ASTR];     // h_prev [b][k] pad, persists step
    __shared__ float sh_att[TENC];
    __shared__ float sh_ectx[TENC];
    __shared__ __align__(16) float sh_u[512];
    __shared__ float sh_z[128];                      // [q32][b]
    __shared__ float sh_cred[2][128];
    __shared__ float sh_red[4];
    __shared__ float sh_hdp[2];

    const float4* st4 = (const float4*)sh_st;
    const float4* h4f = (const float4*)sh_h;
    const float4* u4  = (const float4*)sh_u;

    // one-time staging
    for (int i = tid; i < TENC*128; i += NTHR)
        sh_C[i] = C[((size_t)b_att*TENC + (i >> 7))*DENC + ds*128 + (i & 127)];
    if (tid < TENC) sh_ectx[tid] = ectx_g[b_att*TENC + tid];
    if (tid < 128) ((float4*)sh_u)[tid] = ((const float4*)(u))[tid];
    const float bias_c = bias[sub*512 + jp];

    for (int t = 0; t < TDEC; ++t) {
        // ----- stage x (4 batches), [b][k] coalesced conflict-free -----
        __syncthreads();                                    // guard sh_st reuse
        for (int i = tid; i < 1024; i += NTHR) {
            int bb = i >> 8, kk = i & 255;
            sh_st[bb*ASTR + kk] = inp[((size_t)(bg*4 + bb)*TDEC + t)*DIN + kk];
        }
        __syncthreads();

        // ----- x-part dots: k4 [0,64), all cols -----
        float acc = dotrange<BF>(wpv, cg, col, b, 0, 64, st4, 0, bias_c);

        // ----- waitC(t-1): h ready for this bg -----
        if (t > 0) {
            if (tid == 0) wait16(cnt + (((t-1)*16 + bg) << 2) + 2);
            __syncthreads();
        }
        // ----- stage h_prev (4 batches) -----
        for (int i = tid; i < 2048; i += NTHR) {
            int bb = i >> 9, j = i & 511;
            sh_h[bb*ASTR + j] =
                (t > 0) ? ldA(&hG[(size_t)(bg*4 + bb)*HHH + j]) : 0.f;
        }
        __syncthreads();

        // ----- hd = u . h_prev[b_att] (threads 0..127, waves 0-1) -----
        if (tid < 128) {
            float4 uu = u4[tid];
            float4 hh = ((const float4*)(sh_h + bl_att*ASTR))[tid];
            float p = uu.x*hh.x + uu.y*hh.y + uu.z*hh.z + uu.w*hh.w;
            p = wave_sum(p);
            if ((tid & 63) == 0) sh_hdp[w] = p;
        }
        __syncthreads();
        const float hd = sh_hdp[0] + sh_hdp[1];

        // ----- attention softmax (threads 0..255, matched barriers) -----
        if (tid < TENC) {
            float e = fmaxf(hd + sh_ectx[tid], 0.f);
            float wm = wave_max(e);
            if ((tid & 63) == 0) sh_red[w] = wm;
            __syncthreads();
            float mx = fmaxf(fmaxf(sh_red[0], sh_red[1]), fmaxf(sh_red[2], sh_red[3]));
            float ex = __expf(e - mx);
            float wse = wave_sum(ex);
            __syncthreads();
            if ((tid & 63) == 0) sh_red[w] = wse;
            __syncthreads();
            float dn = sh_red[0] + sh_red[1] + sh_red[2] + sh_red[3];
            sh_att[tid] = ex / dn;
        } else {
            __syncthreads(); __syncthreads(); __syncthreads();
        }
        __syncthreads();

        // ----- ctx slice (b_att, ds) from LDS C; publish -----
        if (tid < TENC) {
            const int dp = tid & 127, hf = tid >> 7;
            const float* Cl = sh_C + (size_t)hf*128*128 + dp;
            float a = 0.f;
#pragma unroll 8
            for (int q = 0; q < 128; ++q)
                a = fmaf(sh_att[hf*128 + q], Cl[(size_t)q*128], a);
            sh_cred[hf][dp] = a;
        }
        __syncthreads();
        if (tid < 128) stA(&ctxG[(size_t)b_att*HHH + ds*128 + tid],
                           sh_cred[0][tid] + sh_cred[1][tid]);
        drain_stores();
        __syncthreads();
        if (tid == 0) arrive(cnt + ((t*16 + bg) << 2) + 0);     // event A

        // ----- h-part dots: k4 [192,320) for z,r cols (overlaps wait A) -----
        if (t > 0 && sub < 2)
            acc = dotrange<BF>(wpv, cg, col, b, 192, 320, h4f, 192, acc);

        // ----- wait A; stage ctx (4 batches); ctx dots k4 [64,192) -----
        if (tid == 0) wait16(cnt + ((t*16 + bg) << 2) + 0);
        __syncthreads();
        for (int i = tid; i < 2048; i += NTHR) {
            int bb = i >> 9, j = i & 511;
            sh_st[bb*ASTR + j] = ldA(&ctxG[(size_t)(bg*4 + bb)*HHH + j]);
        }
        __syncthreads();
        acc = dotrange<BF>(wpv, cg, col, b, 64, 192, st4, 64, acc);

        // ----- z, r finish; publish rh -----
        if (sub == 0) {
            sh_z[q32*4 + b] = 1.f / (1.f + __expf(-acc));
        } else if (sub == 1) {
            float r  = 1.f / (1.f + __expf(-acc));
            float hp = sh_h[b*ASTR + jp];
            stA(&rhG[(size_t)bglob*HHH + jp], r * hp);
        }
        drain_stores();
        __syncthreads();
        if (tid == 0) arrive(cnt + ((t*16 + bg) << 2) + 1);     // event B

        // ----- wait B; stage rh; rh dots for h cols; finish h -----
        if (tid == 0) wait16(cnt + ((t*16 + bg) << 2) + 1);
        __syncthreads();
        for (int i = tid; i < 2048; i += NTHR) {
            int bb = i >> 9, j = i & 511;
            sh_st[bb*ASTR + j] = ldA(&rhG[(size_t)(bg*4 + bb)*HHH + j]);
        }
        __syncthreads();
        if (sub == 2) {
            acc = dotrange<BF>(wpv, cg, col, b, 192, 320, st4, 192, acc);
            float hh = tanhf(acc);
            float z  = sh_z[q32*4 + b];
            float hp = sh_h[b*ASTR + jp];
            float hn = z*hp + (1.f - z)*hh;
            stA(&hG[(size_t)bglob*HHH + jp], hn);
            out[((size_t)bglob*TDEC + t)*HHH + jp] = hn;
        }
        drain_stores();
        __syncthreads();
        if (tid == 0) arrive(cnt + ((t*16 + bg) << 2) + 2);     // event C
    }
}

extern "C" void kernel_launch(void* const* d_in, const int* in_sizes, int n_in,
                              void* d_out, int out_size, void* d_ws, size_t ws_size,
                              hipStream_t stream) {
    const float* inputs = (const float*)d_in[0];
    const float* C      = (const float*)d_in[1];
    const float* w1     = (const float*)d_in[2];
    const float* w2     = (const float*)d_in[3];
    const float* Wx     = (const float*)d_in[4];
    const float* Wh     = (const float*)d_in[5];
    const float* bias   = (const float*)d_in[6];
    float* out = (float*)d_out;
    float* ws  = (float*)d_ws;

    hipMemsetAsync(ws, 0, 128*16*4*sizeof(unsigned), stream);

    k_u   <<<1024, 64,  0, stream>>>(w1, w2, ws + OFF_U);
    k_ectx<<<(64*TENC)/4, 256, 0, stream>>>(C, ws + OFF_U, ws + OFF_ECTX);

    const size_t need_f32 = (size_t)(OFF_WP) * 4u + (size_t)WP_ELEMS * 4u;
    void* wp = (void*)(ws + OFF_WP);
    if (ws_size >= need_f32) {
        k_wpack<false><<<WP_ELEMS/256, 256, 0, stream>>>(Wx, Wh, wp);
        decoder<false><<<NBLK, NTHR, 0, stream>>>(inputs, C, bias, wp,
                                                  ws + OFF_U, ws + OFF_ECTX, out, ws);
    } else {
        k_wpack<true><<<WP_ELEMS/256, 256, 0, stream>>>(Wx, Wh, wp);
        decoder<true><<<NBLK, NTHR, 0, stream>>>(inputs, C, bias, wp,
                                                 ws + OFF_U, ws + OFF_ECTX, out, ws);
    }
}

// Round 12
// 3331.025 us; speedup vs baseline: 1.1833x; 1.1833x over previous
//
#include <hip/hip_runtime.h>

#define NBLK  256
#define NTHR  768
#define TDEC  128
#define TENC  256
#define DIN   256
#define DENC  512
#define HHH   512
#define NG    1536
#define KTOT  1280
#define NK4   320
#define NCOL  384          // 3 gates * 128 cols per js slice

// ws float offsets (same proven layout as round 4/9; total 8.56 MB)
#define OFF_CNT   0                       // 128*3*64 u32 = 24576
#define OFF_HDOT  24576                   // 128*64*4 f32 = 32768
#define OFF_U     57344                   // 1024
#define OFF_ECTX  58368                   // 64*256 = 16384
#define OFF_HG    74752                   // 64*512
#define OFF_CTXG  107520                  // 64*512
#define OFF_RHG   140288                  // 64*512
#define OFF_WP    173056                  // pack: 4*320*384*4 = 1,966,080 elems
#define WP_ELEMS  (4*NK4*NCOL*4)

// ---------------- small helpers ----------------
__device__ __forceinline__ float wave_sum(float v) {
#pragma unroll
    for (int o = 32; o; o >>= 1) v += __shfl_down(v, o, 64);
    return v;
}
__device__ __forceinline__ float wave_max(float v) {
#pragma unroll
    for (int o = 32; o; o >>= 1) v = fmaxf(v, __shfl_down(v, o, 64));
    return v;
}
__device__ __forceinline__ float ldA(float* p) {
    return __hip_atomic_load(p, __ATOMIC_RELAXED, __HIP_MEMORY_SCOPE_AGENT);
}
__device__ __forceinline__ void stA(float* p, float v) {
    __hip_atomic_store(p, v, __ATOMIC_RELAXED, __HIP_MEMORY_SCOPE_AGENT);
}
// drain THIS wave's outstanding vector-memory stores. Every wave that
// published data must do this BEFORE the barrier preceding the arrive.
__device__ __forceinline__ void drain_stores() {
    asm volatile("s_waitcnt vmcnt(0)" ::: "memory");
}
__device__ __forceinline__ void arrive(unsigned* c) {
    asm volatile("s_waitcnt vmcnt(0)" ::: "memory");
    __hip_atomic_fetch_add(c, 1u, __ATOMIC_RELAXED, __HIP_MEMORY_SCOPE_AGENT);
}
__device__ __forceinline__ void wait4(unsigned* c) {
    while (__hip_atomic_load(c, __ATOMIC_RELAXED, __HIP_MEMORY_SCOPE_AGENT) < 4u)
        __builtin_amdgcn_s_sleep(2);
}
__device__ __forceinline__ float blo(unsigned u) { return __uint_as_float(u << 16); }
__device__ __forceinline__ float bhi(unsigned u) { return __uint_as_float(u & 0xffff0000u); }
__device__ __forceinline__ unsigned short f2bf(float f) {
    unsigned u = __float_as_uint(f);
    u += 0x7fffu + ((u >> 16) & 1u);
    return (unsigned short)(u >> 16);
}

// thread's partial dot over k4 in [k4lo,k4hi): weight elem (k4, c), acts a4[k4-aoff].
// dual accumulator chains (k4 step 2) for ILP; ranges are multiples of 32 so even.
template<bool BF>
__device__ __forceinline__ float dotrange(const void* wp, size_t base, int c,
                                          int k4lo, int k4hi, const float4* a4,
                                          int aoff, float acc) {
    const float4* ab = a4 - aoff;
    float acc2 = 0.f;
    if (BF) {
        const uint2* w = (const uint2*)wp + base + c;
#pragma unroll 8
        for (int k4 = k4lo; k4 < k4hi; k4 += 2) {
            uint2 u0 = w[(size_t)k4 * NCOL];
            uint2 u1 = w[(size_t)(k4+1) * NCOL];
            float4 a0 = ab[k4];
            float4 a1 = ab[k4+1];
            acc  = fmaf(blo(u0.x), a0.x, acc);
            acc  = fmaf(bhi(u0.x), a0.y, acc);
            acc  = fmaf(blo(u0.y), a0.z, acc);
            acc  = fmaf(bhi(u0.y), a0.w, acc);
            acc2 = fmaf(blo(u1.x), a1.x, acc2);
            acc2 = fmaf(bhi(u1.x), a1.y, acc2);
            acc2 = fmaf(blo(u1.y), a1.z, acc2);
            acc2 = fmaf(bhi(u1.y), a1.w, acc2);
        }
    } else {
        const float4* w = (const float4*)wp + base + c;
#pragma unroll 8
        for (int k4 = k4lo; k4 < k4hi; k4 += 2) {
            float4 w0 = w[(size_t)k4 * NCOL];
            float4 w1 = w[(size_t)(k4+1) * NCOL];
            float4 a0 = ab[k4];
            float4 a1 = ab[k4+1];
            acc  = fmaf(w0.x, a0.x, acc);
            acc  = fmaf(w0.y, a0.y, acc);
            acc  = fmaf(w0.z, a0.z, acc);
            acc  = fmaf(w0.w, a0.w, acc);
            acc2 = fmaf(w1.x, a1.x, acc2);
            acc2 = fmaf(w1.y, a1.y, acc2);
            acc2 = fmaf(w1.z, a1.z, acc2);
            acc2 = fmaf(w1.w, a1.w, acc2);
        }
    }
    return acc + acc2;
}

// ---------------- precompute kernels ----------------
__global__ void k_u(const float* __restrict__ w1, const float* __restrict__ w2,
                    float* __restrict__ u) {
    int e = blockIdx.x;
    int lane = threadIdx.x;
    float p = 0.f;
#pragma unroll
    for (int k = lane; k < DENC; k += 64) p += w1[e*DENC + k] * w2[k];
    p = wave_sum(p);
    if (lane == 0) u[e] = p;
}

__global__ void k_ectx(const float* __restrict__ C, const float* __restrict__ u,
                       float* __restrict__ ectx) {
    int r = blockIdx.x*4 + (threadIdx.x >> 6);
    int lane = threadIdx.x & 63;
    const float* row = C + (size_t)r*DENC;
    const float* vc  = u + HHH;
    float p = 0.f;
#pragma unroll
    for (int k = 0; k < DENC/64; ++k) p += row[lane + k*64] * vc[lane + k*64];
    p = wave_sum(p);
    if (lane == 0) ectx[r] = p;
}

// K-major pack: layout [js][k4][c][e], k=k4*4+e, col = (c>>7)*512 + js*128 + (c&127)
template<bool BF>
__global__ void k_wpack(const float* __restrict__ Wx, const float* __restrict__ Wh,
                        void* __restrict__ wp) {
    int id = blockIdx.x*256 + threadIdx.x;      // < WP_ELEMS
    int e = id & 3;
    int q = id >> 2;
    int c = q % NCOL;
    q /= NCOL;
    int k4 = q % NK4;
    int js = q / NK4;
    int k = k4*4 + e;
    int col = (c >> 7)*512 + js*128 + (c & 127);
    float v = (k < 768) ? Wx[(size_t)k*NG + col] : Wh[(size_t)(k-768)*NG + col];
    if (BF) ((unsigned short*)wp)[id] = f2bf(v);
    else    ((float*)wp)[id] = v;
}

// ---------------- main kernel ----------------
// 256 blocks: b = blk>>2, js = blk&3.
// 768 threads: ks = tid>=384 (K-split half), c = tid - ks*384.
// col role: sub = c>>7 (0=z,1=r,2=h), jp = c&127.
template<bool BF>
__launch_bounds__(NTHR, 1)
__global__ void decoder(const float* __restrict__ inp, const float* __restrict__ C,
                        const float* __restrict__ bias, const void* __restrict__ wpv,
                        const float* __restrict__ u, float* __restrict__ ectx_g,
                        float* __restrict__ out, float* __restrict__ ws) {
    unsigned* cnt = (unsigned*)ws;
    float* hdotP = ws + OFF_HDOT;
    float* hG    = ws + OFF_HG;
    float* ctxG  = ws + OFF_CTXG;
    float* rhG   = ws + OFF_RHG;

    const int tid = threadIdx.x;
    const int w   = tid >> 6;
    const int b   = blockIdx.x >> 2;
    const int js  = blockIdx.x & 3;
    const int ks  = (tid >= 384);
    const int c   = tid - (ks ? 384 : 0);
    const int sub = c >> 7;
    const int jp  = c & 127;

    __shared__ float sh_C[TENC*128];              // 131 KB: fp32 C slice [q][dp]
    __shared__ __align__(16) float sh_kx[KTOT];   // [0,256)=x  [256,768)=ctx  [768,1280)=h_prev
    __shared__ __align__(16) float sh_rh[HHH];
    __shared__ float sh_att[TENC];
    __shared__ float sh_ectx[TENC];
    __shared__ float sh_u[128];
    __shared__ float sh_z[128];
    __shared__ float sh_part[NCOL];               // K-split partial sums
    __shared__ float sh_cred[2][128];
    __shared__ float sh_red[8];
    __shared__ float sh_scal;

    const float4* kx4 = (const float4*)sh_kx;
    const float4* rh4 = (const float4*)sh_rh;
    const size_t wbase = (size_t)js * NK4 * NCOL;   // in float4/uint2 units

    // one-time staging: fp32 C slice (coalesced rows), ectx, u-slice
    for (int i = tid; i < TENC*128; i += NTHR) {
        int q = i >> 7, dp = i & 127;
        sh_C[i] = C[((size_t)b*TENC + q)*DENC + js*128 + dp];
    }
    if (tid < TENC) sh_ectx[tid] = ectx_g[b*TENC + tid];
    if (tid >= 256 && tid < 384) sh_u[tid - 256] = u[js*128 + (tid - 256)];
    const float bias_c = bias[sub*512 + jp];

    for (int t = 0; t < TDEC; ++t) {
        // ----- stage x_t (independent of events) -----
        __syncthreads();
        if (tid < DIN) sh_kx[tid] = inp[((size_t)b*TDEC + t)*DIN + tid];
        __syncthreads();

        // ----- x-part dots: k4 [0,64) split across ks -----
        float acc = dotrange<BF>(wpv, wbase, c, ks ? 32 : 0, ks ? 64 : 32,
                                 kx4, 0, ks ? 0.f : bias_c);

        // ----- waitC(t-1): h_prev + hdot -----
        if (t > 0) {
            if (tid == 0) {
                wait4(&cnt[((t-1)*3 + 2)*64 + b]);
                float s0 = ldA(&hdotP[(t-1)*256 + b*4 + 0]);
                float s1 = ldA(&hdotP[(t-1)*256 + b*4 + 1]);
                float s2 = ldA(&hdotP[(t-1)*256 + b*4 + 2]);
                float s3 = ldA(&hdotP[(t-1)*256 + b*4 + 3]);
                sh_scal = (s0 + s1) + (s2 + s3);
            }
            __syncthreads();
            for (int i = tid; i < HHH; i += NTHR) sh_kx[768 + i] = ldA(&hG[b*HHH + i]);
        } else {
            if (tid == 0) sh_scal = 0.f;
            for (int i = tid; i < HHH; i += NTHR) sh_kx[768 + i] = 0.f;
        }
        __syncthreads();
        const float hd = sh_scal;

        // ----- attention softmax (threads 0..255, waves 0..3) -----
        if (tid < TENC) {
            float e = fmaxf(hd + sh_ectx[tid], 0.f);
            float wm = wave_max(e);
            if ((tid & 63) == 0) sh_red[w] = wm;
            __syncthreads();
            float mx = fmaxf(fmaxf(sh_red[0], sh_red[1]), fmaxf(sh_red[2], sh_red[3]));
            float ex = __expf(e - mx);
            float wse = wave_sum(ex);
            __syncthreads();
            if ((tid & 63) == 0) sh_red[w] = wse;
            __syncthreads();
            float dn = sh_red[0] + sh_red[1] + sh_red[2] + sh_red[3];
            sh_att[tid] = ex / dn;
        } else {
            __syncthreads(); __syncthreads(); __syncthreads();
        }
        __syncthreads();

        // ----- ctx slice from LDS fp32 C: ctx[js*128+dp] = sum_q att[q]*C[q][dp] -----
        if (tid < TENC) {
            const int dp = tid & 127, hf = tid >> 7;
            const float* Cl = sh_C + (size_t)hf*128*128 + dp;
            float a = 0.f;
#pragma unroll 8
            for (int q = 0; q < 128; ++q)
                a = fmaf(sh_att[hf*128 + q], Cl[(size_t)q*128], a);
            sh_cred[hf][dp] = a;
        }
        __syncthreads();
        if (tid < 128) stA(&ctxG[b*HHH + js*128 + tid], sh_cred[0][tid] + sh_cred[1][tid]);
        drain_stores();                                     // ALL waves drain ctx stores
        __syncthreads();
        if (tid == 0) arrive(&cnt[(t*3 + 0)*64 + b]);       // event A: ctx slice ready

        // ----- h-part dots: k4 [192,320) split, z/r cols (overlaps wait A) -----
        if (t > 0 && sub < 2)
            acc = dotrange<BF>(wpv, wbase, c, ks ? 256 : 192, ks ? 320 : 256,
                               kx4, 0, acc);

        // ----- waitA: stage full ctx, ctx-part dots k4 [64,192) split -----
        if (tid == 0) wait4(&cnt[(t*3 + 0)*64 + b]);
        __syncthreads();
        for (int i = tid; i < HHH; i += NTHR) sh_kx[256 + i] = ldA(&ctxG[b*HHH + i]);
        __syncthreads();
        acc = dotrange<BF>(wpv, wbase, c, ks ? 128 : 64, ks ? 192 : 128,
                           kx4, 0, acc);

        // ----- merge K-split partials for z/r; finish gates; publish rh -----
        if (ks == 1 && sub < 2) sh_part[c] = acc;
        __syncthreads();
        if (ks == 0) {
            if (sub == 0) {
                float a = acc + sh_part[c];
                sh_z[jp] = 1.f / (1.f + __expf(-a));
            } else if (sub == 1) {
                float a = acc + sh_part[c];
                float r = 1.f / (1.f + __expf(-a));
                stA(&rhG[b*HHH + js*128 + jp], r * sh_kx[768 + js*128 + jp]);
            }
        }
        drain_stores();                                     // ALL waves drain rh stores
        __syncthreads();
        if (tid == 0) arrive(&cnt[(t*3 + 1)*64 + b]);       // event B: rh slice ready

        // ----- waitB: stage rh, rh-part dots k4 [192,320) split, gate-h cols -----
        if (tid == 0) wait4(&cnt[(t*3 + 1)*64 + b]);
        __syncthreads();
        for (int i = tid; i < HHH; i += NTHR) sh_rh[i] = ldA(&rhG[b*HHH + i]);
        __syncthreads();

        if (sub == 2)
            acc = dotrange<BF>(wpv, wbase, c, ks ? 256 : 192, ks ? 320 : 256,
                               rh4, 192, acc);
        // merge K-split partials for gate-h; finish h
        if (ks == 1 && sub == 2) sh_part[c] = acc;
        __syncthreads();
        if (ks == 0 && sub == 2) {
            float a  = acc + sh_part[c];
            float hh = tanhf(a);
            float z  = sh_z[jp];
            float hp = sh_kx[768 + js*128 + jp];
            float hn = z*hp + (1.f - z)*hh;
            stA(&hG[b*HHH + js*128 + jp], hn);
            out[((size_t)b*TDEC + t)*HHH + js*128 + jp] = hn;
            float p = sh_u[jp] * hn;
            float s = wave_sum(p);
            if ((tid & 63) == 0) sh_red[w] = s;             // waves 4,5
        }
        drain_stores();                                     // ALL waves drain h stores
        __syncthreads();
        if (tid == 0) {
            stA(&hdotP[t*256 + b*4 + js], sh_red[4] + sh_red[5]);
            arrive(&cnt[(t*3 + 2)*64 + b]);                 // event C: h + hdot ready
        }
    }
}

extern "C" void kernel_launch(void* const* d_in, const int* in_sizes, int n_in,
                              void* d_out, int out_size, void* d_ws, size_t ws_size,
                              hipStream_t stream) {
    const float* inputs = (const float*)d_in[0];
    const float* C      = (const float*)d_in[1];
    const float* w1     = (const float*)d_in[2];
    const float* w2     = (const float*)d_in[3];
    const float* Wx     = (const float*)d_in[4];
    const float* Wh     = (const float*)d_in[5];
    const float* bias   = (const float*)d_in[6];
    float* out = (float*)d_out;
    float* ws  = (float*)d_ws;

    hipMemsetAsync(ws, 0, 128*3*64*sizeof(unsigned), stream);

    k_u   <<<1024, 64,  0, stream>>>(w1, w2, ws + OFF_U);
    k_ectx<<<(64*TENC)/4, 256, 0, stream>>>(C, ws + OFF_U, ws + OFF_ECTX);

    const size_t need_f32 = (size_t)(OFF_WP) * 4u + (size_t)WP_ELEMS * 4u;
    void* wp = (void*)(ws + OFF_WP);
    if (ws_size >= need_f32) {
        k_wpack<false><<<WP_ELEMS/256, 256, 0, stream>>>(Wx, Wh, wp);
        decoder<false><<<NBLK, NTHR, 0, stream>>>(inputs, C, bias, wp,
                                                  ws + OFF_U, ws + OFF_ECTX, out, ws);
    } else {
        k_wpack<true><<<WP_ELEMS/256, 256, 0, stream>>>(Wx, Wh, wp);
        decoder<true><<<NBLK, NTHR, 0, stream>>>(inputs, C, bias, wp,
                                                 ws + OFF_U, ws + OFF_ECTX, out, ws);
    }
}